// Round 9
// baseline (575.219 us; speedup 1.0000x reference)
//
#include <hip/hip_runtime.h>

#define BATCH   262144
#define NCODE   1024
#define DIM     64
#define BLOCK   256
#define NBLK    (BATCH / BLOCK)   // 1024 blocks for emit
#define MARGIN2 2e-5f             // s''-units (= 4e-5 in dist units, validated r2-r8)
#define QCAP    65536

// ws layout (bytes):
// [0, 8192)            double partial[1024]
// [8192, 12288)        float  c2[1024]
// [12288, 12292)       uint   qcount          (pad to 12544)
// [12544, 16640)       float  c2n[1024]       -- c2n[k] = -0.5f*c2[k]
// [16640, 278784)      ushort pack[131072]    -- codebook bf16 hi/lo, fragment-major
// [278784, 540928)     int    queue[65536]
// [540928, 803072)     float  cbT[65536]      -- codebook transposed [d][k]

typedef __attribute__((ext_vector_type(8))) short bf16x8;
typedef __attribute__((ext_vector_type(4))) float f32x4;

#define MFMA(a, b, c) __builtin_amdgcn_mfma_f32_16x16x32_bf16(a, b, c, 0, 0, 0)

// fp32 -> bf16 hi (RNE) + bf16 lo (RNE of exact residual)
__device__ __forceinline__ void split1(float f, unsigned short& h, unsigned short& l) {
    unsigned u = __float_as_uint(f);
    unsigned r = (u + 0x7fffu + ((u >> 16) & 1u)) >> 16;
    h = (unsigned short)r;
    float hf = __uint_as_float(r << 16);
    float lo = f - hf;                      // exact (Sterbenz)
    unsigned u2 = __float_as_uint(lo);
    l = (unsigned short)((u2 + 0x7fffu + ((u2 >> 16) & 1u)) >> 16);
}

// ---- fused prep: qcount zero, cbT transpose, exact c2 (+ -c2/2), pack ----
__global__ __launch_bounds__(256) void prep_kernel(
        const float* __restrict__ cb, float* __restrict__ c2, float* __restrict__ c2n,
        float* __restrict__ cbT, unsigned short* __restrict__ pack,
        unsigned int* __restrict__ qcount)
{
    const int gid = blockIdx.x * 256 + threadIdx.x;           // 0..65535
    if (gid == 0) *qcount = 0u;                               // re-zero each replay
    // transpose: cbT[d][k] = cb[k][d]
    cbT[(size_t)(gid & 63) * NCODE + (gid >> 6)] = cb[gid];
    // exact c2 (numpy pairwise order, 8 accumulators) — verified
    if (gid < NCODE) {
        const float* row = cb + (size_t)gid * DIM;
        float r[8];
#pragma unroll
        for (int j = 0; j < 8; ++j) r[j] = __fmul_rn(row[j], row[j]);
#pragma unroll
        for (int i = 8; i < DIM; i += 8) {
#pragma unroll
            for (int j = 0; j < 8; ++j) r[j] = __fadd_rn(r[j], __fmul_rn(row[i + j], row[i + j]));
        }
        const float v = __fadd_rn(__fadd_rn(__fadd_rn(r[0], r[1]), __fadd_rn(r[2], r[3])),
                                  __fadd_rn(__fadd_rn(r[4], r[5]), __fadd_rn(r[6], r[7])));
        c2[gid] = v;
        c2n[gid] = -0.5f * v;                 // exact scaling, screen-side only
    }
    // pack: fragment-major bf16 hi/lo
    if (gid < 4096) {
        const int t = gid >> 6, lane = gid & 63;
        const int c = t * 16 + (lane & 15);
        const int g = lane >> 4;
#pragma unroll
        for (int s = 0; s < 2; ++s) {
            const float* src = cb + (size_t)c * DIM + s * 32 + g * 8;
            bf16x8 hv, lv;
#pragma unroll
            for (int j = 0; j < 8; ++j) {
                unsigned short hh, ll; split1(src[j], hh, ll);
                hv[j] = (short)hh; lv[j] = (short)ll;
            }
            *(bf16x8*)(pack + ((size_t)(t * 4 + 2 * s + 0) * 64 + lane) * 8) = hv;
            *(bf16x8*)(pack + ((size_t)(t * 4 + 2 * s + 1) * 64 + lane) * 8) = lv;
        }
    }
}

// ---- MFMA screening (r5-verified, 120 us): best/2nd of s''(k) = cross - c2/2 ----
// argmax(s'') == argmin(dist). wave = 32 rows (2 row-tiles); block = 4 waves; grid 2048.
// B staged via global_load_lds into double-buffered 16 KB chunks; prefetch next chunk
// before computing current; single __syncthreads per chunk.
__global__ __launch_bounds__(256) void screen_kernel(
        const float* __restrict__ z, const unsigned short* __restrict__ pack,
        const float* __restrict__ c2n, float* __restrict__ out_idx,
        int* __restrict__ queue, unsigned int* __restrict__ qcount)
{
    __shared__ __align__(16) unsigned short lds[2][8192];   // 2 x 16 KB chunks
    const int tid  = threadIdx.x;
    const int lane = tid & 63, wid = tid >> 6;
    const int col  = lane & 15, g = lane >> 4;
    const int rowbase = blockIdx.x * 128 + wid * 32;

    // A-frags: A[row = lane&15][k = 32*s + 8*g + j], in VGPRs for whole kernel
    bf16x8 Ah[2][2], Al[2][2];
#pragma unroll
    for (int rt = 0; rt < 2; ++rt)
#pragma unroll
        for (int s = 0; s < 2; ++s) {
            const float* zp = z + (size_t)(rowbase + rt * 16 + col) * DIM + s * 32 + g * 8;
            float tmp[8];
            *(float4*)(tmp)     = ((const float4*)zp)[0];
            *(float4*)(tmp + 4) = ((const float4*)zp)[1];
            bf16x8 hv, lv;
#pragma unroll
            for (int j = 0; j < 8; ++j) {
                unsigned short hh, ll; split1(tmp[j], hh, ll);
                hv[j] = (short)hh; lv[j] = (short)ll;
            }
            Ah[rt][s] = hv; Al[rt][s] = lv;
        }

    float b1[8], b2[8], bk[8];
#pragma unroll
    for (int i = 0; i < 8; ++i) {
        b1[i] = -__builtin_inff(); b2[i] = -__builtin_inff(); bk[i] = 0.f;
    }
    float codef = (float)col;

    // max-tracking; b2 = med3(s, b1_old, b2) is exact 2nd-max update given b2 <= b1
#define UPD(i, sv) { const float s_ = (sv); \
                     bk[i] = (s_ > b1[i]) ? codef : bk[i]; \
                     b2[i] = __builtin_amdgcn_fmed3f(s_, b1[i], b2[i]); \
                     b1[i] = fmaxf(b1[i], s_); }

    // stage one 16 KB chunk (4 tiles) via global_load_lds, 4 x 1KB segs per wave
#define STAGE(c, buf) { \
_Pragma("unroll") \
        for (int i_ = 0; i_ < 4; ++i_) { \
            const int seg_ = wid * 4 + i_; \
            const unsigned short* g_ = pack + (size_t)(c) * 8192 + seg_ * 512 + lane * 8; \
            unsigned short* l_ = &lds[buf][seg_ * 512]; \
            __builtin_amdgcn_global_load_lds( \
                (const __attribute__((address_space(1))) unsigned int*)g_, \
                (__attribute__((address_space(3))) unsigned int*)l_, 16, 0, 0); \
        } }

    int cur = 0;
    STAGE(0, 0);
    __syncthreads();
#pragma unroll 1
    for (int c = 0; c < 16; ++c) {
        if (c < 15) STAGE(c + 1, cur ^ 1);          // prefetch under compute
        float c2r[4];
#pragma unroll
        for (int u = 0; u < 4; ++u) c2r[u] = c2n[(c * 4 + u) * 16 + col];
        const unsigned short* buf = &lds[cur][0];
#pragma unroll
        for (int u = 0; u < 4; ++u) {
            const unsigned short* lb = buf + u * 2048;
            bf16x8 Bh0 = *(const bf16x8*)(lb +    0 + lane * 8);
            bf16x8 Bl0 = *(const bf16x8*)(lb +  512 + lane * 8);
            bf16x8 Bh1 = *(const bf16x8*)(lb + 1024 + lane * 8);
            bf16x8 Bl1 = *(const bf16x8*)(lb + 1536 + lane * 8);
            const float cv = c2r[u];
#pragma unroll
            for (int rt = 0; rt < 2; ++rt) {
                f32x4 acc = {cv, cv, cv, cv};       // C-in = -c2/2 (folds the fma away)
                // cross = zhi*chi + zhi*clo + zlo*chi (lo*lo dropped, ~2^-18 rel)
                acc = MFMA(Ah[rt][0], Bh0, acc); acc = MFMA(Ah[rt][1], Bh1, acc);
                acc = MFMA(Ah[rt][0], Bl0, acc); acc = MFMA(Al[rt][0], Bh0, acc);
                acc = MFMA(Ah[rt][1], Bl1, acc); acc = MFMA(Al[rt][1], Bh1, acc);
#pragma unroll
                for (int reg = 0; reg < 4; ++reg) UPD(rt * 4 + reg, acc[reg]);
            }
            codef += 16.f;
        }
        __syncthreads();                            // drains prefetch + WAR fence
        cur ^= 1;
    }
#undef UPD
#undef STAGE

    // reduce (b1, bk, b2) across the 16 lanes holding one row's 16 col-classes (max form)
#pragma unroll
    for (int i = 0; i < 8; ++i) {
        float v1 = b1[i], v2 = b2[i], vk = bk[i];
#pragma unroll
        for (int m = 1; m < 16; m <<= 1) {
            const float o1 = __shfl_xor(v1, m);
            const float o2 = __shfl_xor(v2, m);
            const float ok = __shfl_xor(vk, m);
            v2 = fmaxf(fmaxf(v2, o2), fminf(v1, o1));
            if (o1 > v1) vk = ok;                   // exact tie keeps own; tie flagged anyway
            v1 = fmaxf(v1, o1);
        }
        if (col == 0) {
            const int rt = i >> 2, reg = i & 3;
            const int row = rowbase + rt * 16 + g * 4 + reg;
            out_idx[row] = vk;
            if (v1 - v2 <= MARGIN2) {
                unsigned int p = atomicAdd(qcount, 1u);
                if (p < QCAP) queue[p] = row;
            }
        }
    }
}

// ---- exact fix-up: ONE WAVE per flagged row, zero barriers ----
// lane owns 16 contiguous codes (4 groups x float4 from cbT, coalesced, L2-hit).
// Per-k math byte-identical to the verified path: ascending-d FMA chain,
// fadd(fma(-2,a,z2), c2[k]), strict <, ascending k; cross-lane first-index ties.
__device__ __forceinline__ void fix_row_wave(
        int row, int lane, const float* __restrict__ z, const float* __restrict__ cbT,
        const float* __restrict__ c2, float* __restrict__ out_idx)
{
    // z row broadcast into registers (same-address loads across lanes -> L1 broadcast)
    float zv[DIM];
    const float4* zp = (const float4*)(z + (size_t)row * DIM);
#pragma unroll
    for (int i = 0; i < 16; ++i) {
        float4 v = zp[i];
        zv[4 * i] = v.x; zv[4 * i + 1] = v.y; zv[4 * i + 2] = v.z; zv[4 * i + 3] = v.w;
    }
    // z2: numpy pairwise, 8 accumulators (verified order)
    float ra[8];
#pragma unroll
    for (int j = 0; j < 8; ++j) ra[j] = __fmul_rn(zv[j], zv[j]);
#pragma unroll
    for (int d = 8; d < DIM; d += 8) {
#pragma unroll
        for (int j = 0; j < 8; ++j) ra[j] = __fadd_rn(ra[j], __fmul_rn(zv[d + j], zv[d + j]));
    }
    const float z2 = __fadd_rn(__fadd_rn(__fadd_rn(ra[0], ra[1]), __fadd_rn(ra[2], ra[3])),
                               __fadd_rn(__fadd_rn(ra[4], ra[5]), __fadd_rn(ra[6], ra[7])));

    float best = __builtin_inff();
    int bestk = NCODE;
#pragma unroll
    for (int gq = 0; gq < 4; ++gq) {                 // 4 groups of 4 codes, ascending k
        const int k0 = lane * 16 + gq * 4;
        float a0 = 0.f, a1 = 0.f, a2 = 0.f, a3 = 0.f;
#pragma unroll
        for (int d = 0; d < DIM; ++d) {              // ascending d, sequential FMA chains
            const float4 cv = *(const float4*)(cbT + (size_t)d * NCODE + k0);
            const float zd = zv[d];
            a0 = __fmaf_rn(zd, cv.x, a0);
            a1 = __fmaf_rn(zd, cv.y, a1);
            a2 = __fmaf_rn(zd, cv.z, a2);
            a3 = __fmaf_rn(zd, cv.w, a3);
        }
        float aa[4] = {a0, a1, a2, a3};
#pragma unroll
        for (int j = 0; j < 4; ++j) {
            const float dist = __fadd_rn(__fmaf_rn(-2.0f, aa[j], z2), c2[k0 + j]);
            if (dist < best) { best = dist; bestk = k0 + j; }   // strict <, ascending k
        }
    }
    // cross-lane exact min with first-index tie-break (lanes hold disjoint k-ranges)
#pragma unroll
    for (int m = 1; m < 64; m <<= 1) {
        const float ob = __shfl_xor(best, m);
        const int   ok = __shfl_xor(bestk, m);
        if (ob < best || (ob == best && ok < bestk)) { best = ob; bestk = ok; }
    }
    if (lane == 0) out_idx[row] = (float)bestk;
}

__global__ __launch_bounds__(256) void fix_kernel(
        const float* __restrict__ z, const float* __restrict__ cbT,
        const float* __restrict__ c2, const int* __restrict__ queue,
        const unsigned int* __restrict__ qcount, float* __restrict__ out_idx)
{
    const int lane = threadIdx.x & 63;
    const int wv = blockIdx.x * (BLOCK / 64) + (threadIdx.x >> 6);
    const int nw = gridDim.x * (BLOCK / 64);
    const unsigned int nq = *qcount;
    if (nq <= QCAP) {
        for (unsigned int qi = wv; qi < nq; qi += nw)
            fix_row_wave(queue[qi], lane, z, cbT, c2, out_idx);
    } else {
        // overflow fallback (never expected): exact-fix every row
        for (int row = wv; row < BATCH; row += nw)
            fix_row_wave(row, lane, z, cbT, c2, out_idx);
    }
}

// ---- epilogue: gather z_q, straight-through output, loss partial (verbatim) ----
__global__ __launch_bounds__(BLOCK) void emit_kernel(
        const float* __restrict__ z, const float* __restrict__ cb,
        const float* __restrict__ out_idx, float* __restrict__ out_zq,
        double* __restrict__ partial)
{
    const int b = blockIdx.x * BLOCK + threadIdx.x;
    const int bestk = (int)out_idx[b];
    const float* cq = cb + (size_t)bestk * DIM;
    const float4* zv = (const float4*)(z + (size_t)b * DIM);
    const float4* qv = (const float4*)cq;
    float4* ov = (float4*)(out_zq + (size_t)b * DIM);
    double lsum = 0.0;
#pragma unroll
    for (int i = 0; i < DIM / 4; ++i) {
        float4 qq = qv[i], zl = zv[i];
        float qa[4] = {qq.x, qq.y, qq.z, qq.w};
        float za[4] = {zl.x, zl.y, zl.z, zl.w};
        float o[4];
#pragma unroll
        for (int j = 0; j < 4; ++j) {
            const float t = __fsub_rn(qa[j], za[j]);
            o[j] = __fadd_rn(za[j], t);
            lsum += (double)t * (double)t;
        }
        float4 vv; vv.x = o[0]; vv.y = o[1]; vv.z = o[2]; vv.w = o[3];
        ov[i] = vv;
    }

    __shared__ double sred[BLOCK];
    sred[threadIdx.x] = lsum;
    __syncthreads();
#pragma unroll
    for (int s = BLOCK / 2; s > 0; s >>= 1) {
        if (threadIdx.x < s) sred[threadIdx.x] += sred[threadIdx.x + s];
        __syncthreads();
    }
    if (threadIdx.x == 0) partial[blockIdx.x] = sred[0];
}

__global__ void loss_kernel(const double* __restrict__ partial, float* __restrict__ out_loss) {
    __shared__ double sred[256];
    double s = 0.0;
    for (int i = threadIdx.x; i < NBLK; i += 256) s += partial[i];
    sred[threadIdx.x] = s;
    __syncthreads();
#pragma unroll
    for (int st = 128; st > 0; st >>= 1) {
        if (threadIdx.x < st) sred[threadIdx.x] += sred[threadIdx.x + st];
        __syncthreads();
    }
    if (threadIdx.x == 0) {
        const double mean = sred[0] / (double)((size_t)BATCH * DIM);
        const float L = (float)mean;
        out_loss[0] = __fadd_rn(L, __fmul_rn(0.25f, L));
    }
}

extern "C" void kernel_launch(void* const* d_in, const int* in_sizes, int n_in,
                              void* d_out, int out_size, void* d_ws, size_t ws_size,
                              hipStream_t stream) {
    (void)in_sizes; (void)n_in; (void)out_size; (void)ws_size;
    const float* z  = (const float*)d_in[0];
    const float* cb = (const float*)d_in[1];
    float* out      = (float*)d_out;
    float* out_zq   = out;
    float* out_loss = out + (size_t)BATCH * DIM;
    float* out_idx  = out + (size_t)BATCH * DIM + 1;
    double* partial = (double*)d_ws;
    float* c2       = (float*)((char*)d_ws + 8192);
    unsigned int* qcount = (unsigned int*)((char*)d_ws + 12288);
    float* c2n      = (float*)((char*)d_ws + 12544);
    unsigned short* pack = (unsigned short*)((char*)d_ws + 16640);
    int* queue      = (int*)((char*)d_ws + 278784);
    float* cbT      = (float*)((char*)d_ws + 540928);

    prep_kernel<<<256, 256, 0, stream>>>(cb, c2, c2n, cbT, pack, qcount);
    screen_kernel<<<BATCH / 128, 256, 0, stream>>>(z, pack, c2n, out_idx, queue, qcount);
    fix_kernel<<<2048, 256, 0, stream>>>(z, cbT, c2, queue, qcount, out_idx);
    emit_kernel<<<NBLK, BLOCK, 0, stream>>>(z, cb, out_idx, out_zq, partial);
    loss_kernel<<<1, 256, 0, stream>>>(partial, out_loss);
}

// Round 10
// 331.218 us; speedup vs baseline: 1.7367x; 1.7367x over previous
//
#include <hip/hip_runtime.h>

#define BATCH   262144
#define NCODE   1024
#define DIM     64
#define BLOCK   256
#define NBLK    (BATCH / BLOCK)   // 1024 blocks for emit
#define MARGIN2 2e-5f             // s''-units (= 4e-5 in dist units, validated r2-r9)
#define QCAP    65536

// ws layout (bytes):
// [0, 8192)            double partial[1024]
// [8192, 12288)        float  c2[1024]
// [12288, 12292)       uint   qcount          (pad to 12544)
// [12544, 16640)       float  c2n[1024]       -- c2n[k] = -0.5f*c2[k]
// [16640, 278784)      ushort pack[131072]    -- codebook bf16 hi/lo, fragment-major
// [278784, 540928)     int    queue[65536]
// [540928, 803072)     float  cbT[65536]      -- codebook transposed [d][k]

typedef __attribute__((ext_vector_type(8))) short bf16x8;
typedef __attribute__((ext_vector_type(4))) float f32x4;

#define MFMA(a, b, c) __builtin_amdgcn_mfma_f32_16x16x32_bf16(a, b, c, 0, 0, 0)

// fp32 -> bf16 hi (RNE) + bf16 lo (RNE of exact residual)
__device__ __forceinline__ void split1(float f, unsigned short& h, unsigned short& l) {
    unsigned u = __float_as_uint(f);
    unsigned r = (u + 0x7fffu + ((u >> 16) & 1u)) >> 16;
    h = (unsigned short)r;
    float hf = __uint_as_float(r << 16);
    float lo = f - hf;                      // exact (Sterbenz)
    unsigned u2 = __float_as_uint(lo);
    l = (unsigned short)((u2 + 0x7fffu + ((u2 >> 16) & 1u)) >> 16);
}

// ---- fused prep: qcount zero, cbT transpose, exact c2 (+ -c2/2), pack ----
__global__ __launch_bounds__(256) void prep_kernel(
        const float* __restrict__ cb, float* __restrict__ c2, float* __restrict__ c2n,
        float* __restrict__ cbT, unsigned short* __restrict__ pack,
        unsigned int* __restrict__ qcount)
{
    const int gid = blockIdx.x * 256 + threadIdx.x;           // 0..65535
    if (gid == 0) *qcount = 0u;                               // re-zero each replay
    // transpose: cbT[d][k] = cb[k][d]
    cbT[(size_t)(gid & 63) * NCODE + (gid >> 6)] = cb[gid];
    // exact c2 (numpy pairwise order, 8 accumulators) — verified
    if (gid < NCODE) {
        const float* row = cb + (size_t)gid * DIM;
        float r[8];
#pragma unroll
        for (int j = 0; j < 8; ++j) r[j] = __fmul_rn(row[j], row[j]);
#pragma unroll
        for (int i = 8; i < DIM; i += 8) {
#pragma unroll
            for (int j = 0; j < 8; ++j) r[j] = __fadd_rn(r[j], __fmul_rn(row[i + j], row[i + j]));
        }
        const float v = __fadd_rn(__fadd_rn(__fadd_rn(r[0], r[1]), __fadd_rn(r[2], r[3])),
                                  __fadd_rn(__fadd_rn(r[4], r[5]), __fadd_rn(r[6], r[7])));
        c2[gid] = v;
        c2n[gid] = -0.5f * v;                 // exact scaling, screen-side only
    }
    // pack: fragment-major bf16 hi/lo
    if (gid < 4096) {
        const int t = gid >> 6, lane = gid & 63;
        const int c = t * 16 + (lane & 15);
        const int g = lane >> 4;
#pragma unroll
        for (int s = 0; s < 2; ++s) {
            const float* src = cb + (size_t)c * DIM + s * 32 + g * 8;
            bf16x8 hv, lv;
#pragma unroll
            for (int j = 0; j < 8; ++j) {
                unsigned short hh, ll; split1(src[j], hh, ll);
                hv[j] = (short)hh; lv[j] = (short)ll;
            }
            *(bf16x8*)(pack + ((size_t)(t * 4 + 2 * s + 0) * 64 + lane) * 8) = hv;
            *(bf16x8*)(pack + ((size_t)(t * 4 + 2 * s + 1) * 64 + lane) * 8) = lv;
        }
    }
}

// ---- MFMA screening (r5-verified, 120 us): best/2nd of s''(k) = cross - c2/2 ----
// argmax(s'') == argmin(dist). wave = 32 rows (2 row-tiles); block = 4 waves; grid 2048.
// B staged via global_load_lds into double-buffered 16 KB chunks; prefetch next chunk
// before computing current; single __syncthreads per chunk.
__global__ __launch_bounds__(256) void screen_kernel(
        const float* __restrict__ z, const unsigned short* __restrict__ pack,
        const float* __restrict__ c2n, float* __restrict__ out_idx,
        int* __restrict__ queue, unsigned int* __restrict__ qcount)
{
    __shared__ __align__(16) unsigned short lds[2][8192];   // 2 x 16 KB chunks
    const int tid  = threadIdx.x;
    const int lane = tid & 63, wid = tid >> 6;
    const int col  = lane & 15, g = lane >> 4;
    const int rowbase = blockIdx.x * 128 + wid * 32;

    // A-frags: A[row = lane&15][k = 32*s + 8*g + j], in VGPRs for whole kernel
    bf16x8 Ah[2][2], Al[2][2];
#pragma unroll
    for (int rt = 0; rt < 2; ++rt)
#pragma unroll
        for (int s = 0; s < 2; ++s) {
            const float* zp = z + (size_t)(rowbase + rt * 16 + col) * DIM + s * 32 + g * 8;
            float tmp[8];
            *(float4*)(tmp)     = ((const float4*)zp)[0];
            *(float4*)(tmp + 4) = ((const float4*)zp)[1];
            bf16x8 hv, lv;
#pragma unroll
            for (int j = 0; j < 8; ++j) {
                unsigned short hh, ll; split1(tmp[j], hh, ll);
                hv[j] = (short)hh; lv[j] = (short)ll;
            }
            Ah[rt][s] = hv; Al[rt][s] = lv;
        }

    float b1[8], b2[8], bk[8];
#pragma unroll
    for (int i = 0; i < 8; ++i) {
        b1[i] = -__builtin_inff(); b2[i] = -__builtin_inff(); bk[i] = 0.f;
    }
    float codef = (float)col;

    // max-tracking; b2 = med3(s, b1_old, b2) is exact 2nd-max update given b2 <= b1
#define UPD(i, sv) { const float s_ = (sv); \
                     bk[i] = (s_ > b1[i]) ? codef : bk[i]; \
                     b2[i] = __builtin_amdgcn_fmed3f(s_, b1[i], b2[i]); \
                     b1[i] = fmaxf(b1[i], s_); }

    // stage one 16 KB chunk (4 tiles) via global_load_lds, 4 x 1KB segs per wave
#define STAGE(c, buf) { \
_Pragma("unroll") \
        for (int i_ = 0; i_ < 4; ++i_) { \
            const int seg_ = wid * 4 + i_; \
            const unsigned short* g_ = pack + (size_t)(c) * 8192 + seg_ * 512 + lane * 8; \
            unsigned short* l_ = &lds[buf][seg_ * 512]; \
            __builtin_amdgcn_global_load_lds( \
                (const __attribute__((address_space(1))) unsigned int*)g_, \
                (__attribute__((address_space(3))) unsigned int*)l_, 16, 0, 0); \
        } }

    int cur = 0;
    STAGE(0, 0);
    __syncthreads();
#pragma unroll 1
    for (int c = 0; c < 16; ++c) {
        if (c < 15) STAGE(c + 1, cur ^ 1);          // prefetch under compute
        float c2r[4];
#pragma unroll
        for (int u = 0; u < 4; ++u) c2r[u] = c2n[(c * 4 + u) * 16 + col];
        const unsigned short* buf = &lds[cur][0];
#pragma unroll
        for (int u = 0; u < 4; ++u) {
            const unsigned short* lb = buf + u * 2048;
            bf16x8 Bh0 = *(const bf16x8*)(lb +    0 + lane * 8);
            bf16x8 Bl0 = *(const bf16x8*)(lb +  512 + lane * 8);
            bf16x8 Bh1 = *(const bf16x8*)(lb + 1024 + lane * 8);
            bf16x8 Bl1 = *(const bf16x8*)(lb + 1536 + lane * 8);
            const float cv = c2r[u];
#pragma unroll
            for (int rt = 0; rt < 2; ++rt) {
                f32x4 acc = {cv, cv, cv, cv};       // C-in = -c2/2 (folds the fma away)
                // cross = zhi*chi + zhi*clo + zlo*chi (lo*lo dropped, ~2^-18 rel)
                acc = MFMA(Ah[rt][0], Bh0, acc); acc = MFMA(Ah[rt][1], Bh1, acc);
                acc = MFMA(Ah[rt][0], Bl0, acc); acc = MFMA(Al[rt][0], Bh0, acc);
                acc = MFMA(Ah[rt][1], Bl1, acc); acc = MFMA(Al[rt][1], Bh1, acc);
#pragma unroll
                for (int reg = 0; reg < 4; ++reg) UPD(rt * 4 + reg, acc[reg]);
            }
            codef += 16.f;
        }
        __syncthreads();                            // drains prefetch + WAR fence
        cur ^= 1;
    }
#undef UPD
#undef STAGE

    // reduce (b1, bk, b2) across the 16 lanes holding one row's 16 col-classes (max form)
#pragma unroll
    for (int i = 0; i < 8; ++i) {
        float v1 = b1[i], v2 = b2[i], vk = bk[i];
#pragma unroll
        for (int m = 1; m < 16; m <<= 1) {
            const float o1 = __shfl_xor(v1, m);
            const float o2 = __shfl_xor(v2, m);
            const float ok = __shfl_xor(vk, m);
            v2 = fmaxf(fmaxf(v2, o2), fminf(v1, o1));
            if (o1 > v1) vk = ok;                   // exact tie keeps own; tie flagged anyway
            v1 = fmaxf(v1, o1);
        }
        if (col == 0) {
            const int rt = i >> 2, reg = i & 3;
            const int row = rowbase + rt * 16 + g * 4 + reg;
            out_idx[row] = vk;
            if (v1 - v2 <= MARGIN2) {
                unsigned int p = atomicAdd(qcount, 1u);
                if (p < QCAP) queue[p] = row;
            }
        }
    }
}

// ---- exact fix-up: ONE WAVE per flagged row, zero bulk register state ----
// Lane l holds only z[row*64+l]; all z uses go through __shfl broadcast.
// d-outer loop: per d, lane loads its 4 contiguous float4 of the cbT row
// (wave covers the 4 KB row coalesced, L2-hot) and runs 16 FMA chains.
// Per-code math byte-identical to the verified path: ascending-d sequential FMA,
// fadd(fma(-2,a,z2), c2[k]), strict <, ascending k; cross-lane first-index ties.
__device__ __forceinline__ void fix_row_wave(
        int row, int lane, const float* __restrict__ z, const float* __restrict__ cbT,
        const float* __restrict__ c2, float* __restrict__ out_idx)
{
    const float zl = z[(size_t)row * DIM + lane];     // one coalesced 256B wave-load

    // z2 in exact numpy pairwise order (8 accumulators over stride-8 groups),
    // reconstructed redundantly per-lane via shfl broadcasts
    float r[8];
#pragma unroll
    for (int j = 0; j < 8; ++j) {
        const float v = __shfl(zl, j);
        r[j] = __fmul_rn(v, v);
    }
#pragma unroll
    for (int i = 1; i < 8; ++i) {
#pragma unroll
        for (int j = 0; j < 8; ++j) {
            const float v = __shfl(zl, 8 * i + j);
            r[j] = __fadd_rn(r[j], __fmul_rn(v, v));
        }
    }
    const float z2 = __fadd_rn(__fadd_rn(__fadd_rn(r[0], r[1]), __fadd_rn(r[2], r[3])),
                               __fadd_rn(__fadd_rn(r[4], r[5]), __fadd_rn(r[6], r[7])));

    // 16 contiguous codes per lane: k = lane*16 + i, 16 independent FMA chains
    float aa[16];
#pragma unroll
    for (int i = 0; i < 16; ++i) aa[i] = 0.f;
#pragma unroll 2
    for (int d = 0; d < DIM; ++d) {                   // ascending d (sequential chains)
        const float zd = __shfl(zl, d);
        const float4* rowp = (const float4*)(cbT + (size_t)d * NCODE + lane * 16);
#pragma unroll
        for (int q = 0; q < 4; ++q) {
            const float4 cv = rowp[q];
            aa[4 * q + 0] = __fmaf_rn(zd, cv.x, aa[4 * q + 0]);
            aa[4 * q + 1] = __fmaf_rn(zd, cv.y, aa[4 * q + 1]);
            aa[4 * q + 2] = __fmaf_rn(zd, cv.z, aa[4 * q + 2]);
            aa[4 * q + 3] = __fmaf_rn(zd, cv.w, aa[4 * q + 3]);
        }
    }
    float best = __builtin_inff();
    int bestk = NCODE;
#pragma unroll
    for (int i = 0; i < 16; ++i) {                    // ascending k within lane
        const int k = lane * 16 + i;
        const float dist = __fadd_rn(__fmaf_rn(-2.0f, aa[i], z2), c2[k]);
        if (dist < best) { best = dist; bestk = k; }  // strict < keeps first index
    }
    // cross-lane exact min with first-index tie-break (lanes hold disjoint k-ranges)
#pragma unroll
    for (int m = 1; m < 64; m <<= 1) {
        const float ob = __shfl_xor(best, m);
        const int   ok = __shfl_xor(bestk, m);
        if (ob < best || (ob == best && ok < bestk)) { best = ob; bestk = ok; }
    }
    if (lane == 0) out_idx[row] = (float)bestk;
}

__global__ __launch_bounds__(256) void fix_kernel(
        const float* __restrict__ z, const float* __restrict__ cbT,
        const float* __restrict__ c2, const int* __restrict__ queue,
        const unsigned int* __restrict__ qcount, float* __restrict__ out_idx)
{
    const int lane = threadIdx.x & 63;
    const int wv = blockIdx.x * (BLOCK / 64) + (threadIdx.x >> 6);
    const int nw = gridDim.x * (BLOCK / 64);
    const unsigned int nq = *qcount;
    if (nq <= QCAP) {
        for (unsigned int qi = wv; qi < nq; qi += nw)
            fix_row_wave(queue[qi], lane, z, cbT, c2, out_idx);
    } else {
        // overflow fallback (never expected): exact-fix every row
        for (int row = wv; row < BATCH; row += nw)
            fix_row_wave(row, lane, z, cbT, c2, out_idx);
    }
}

// ---- epilogue: gather z_q, straight-through output, loss partial (verbatim) ----
__global__ __launch_bounds__(BLOCK) void emit_kernel(
        const float* __restrict__ z, const float* __restrict__ cb,
        const float* __restrict__ out_idx, float* __restrict__ out_zq,
        double* __restrict__ partial)
{
    const int b = blockIdx.x * BLOCK + threadIdx.x;
    const int bestk = (int)out_idx[b];
    const float* cq = cb + (size_t)bestk * DIM;
    const float4* zv = (const float4*)(z + (size_t)b * DIM);
    const float4* qv = (const float4*)cq;
    float4* ov = (float4*)(out_zq + (size_t)b * DIM);
    double lsum = 0.0;
#pragma unroll
    for (int i = 0; i < DIM / 4; ++i) {
        float4 qq = qv[i], zl = zv[i];
        float qa[4] = {qq.x, qq.y, qq.z, qq.w};
        float za[4] = {zl.x, zl.y, zl.z, zl.w};
        float o[4];
#pragma unroll
        for (int j = 0; j < 4; ++j) {
            const float t = __fsub_rn(qa[j], za[j]);
            o[j] = __fadd_rn(za[j], t);
            lsum += (double)t * (double)t;
        }
        float4 vv; vv.x = o[0]; vv.y = o[1]; vv.z = o[2]; vv.w = o[3];
        ov[i] = vv;
    }

    __shared__ double sred[BLOCK];
    sred[threadIdx.x] = lsum;
    __syncthreads();
#pragma unroll
    for (int s = BLOCK / 2; s > 0; s >>= 1) {
        if (threadIdx.x < s) sred[threadIdx.x] += sred[threadIdx.x + s];
        __syncthreads();
    }
    if (threadIdx.x == 0) partial[blockIdx.x] = sred[0];
}

__global__ void loss_kernel(const double* __restrict__ partial, float* __restrict__ out_loss) {
    __shared__ double sred[256];
    double s = 0.0;
    for (int i = threadIdx.x; i < NBLK; i += 256) s += partial[i];
    sred[threadIdx.x] = s;
    __syncthreads();
#pragma unroll
    for (int st = 128; st > 0; st >>= 1) {
        if (threadIdx.x < st) sred[threadIdx.x] += sred[threadIdx.x + st];
        __syncthreads();
    }
    if (threadIdx.x == 0) {
        const double mean = sred[0] / (double)((size_t)BATCH * DIM);
        const float L = (float)mean;
        out_loss[0] = __fadd_rn(L, __fmul_rn(0.25f, L));
    }
}

extern "C" void kernel_launch(void* const* d_in, const int* in_sizes, int n_in,
                              void* d_out, int out_size, void* d_ws, size_t ws_size,
                              hipStream_t stream) {
    (void)in_sizes; (void)n_in; (void)out_size; (void)ws_size;
    const float* z  = (const float*)d_in[0];
    const float* cb = (const float*)d_in[1];
    float* out      = (float*)d_out;
    float* out_zq   = out;
    float* out_loss = out + (size_t)BATCH * DIM;
    float* out_idx  = out + (size_t)BATCH * DIM + 1;
    double* partial = (double*)d_ws;
    float* c2       = (float*)((char*)d_ws + 8192);
    unsigned int* qcount = (unsigned int*)((char*)d_ws + 12288);
    float* c2n      = (float*)((char*)d_ws + 12544);
    unsigned short* pack = (unsigned short*)((char*)d_ws + 16640);
    int* queue      = (int*)((char*)d_ws + 278784);
    float* cbT      = (float*)((char*)d_ws + 540928);

    prep_kernel<<<256, 256, 0, stream>>>(cb, c2, c2n, cbT, pack, qcount);
    screen_kernel<<<BATCH / 128, 256, 0, stream>>>(z, pack, c2n, out_idx, queue, qcount);
    fix_kernel<<<2048, 256, 0, stream>>>(z, cbT, c2, queue, qcount, out_idx);
    emit_kernel<<<NBLK, BLOCK, 0, stream>>>(z, cb, out_idx, out_zq, partial);
    loss_kernel<<<1, 256, 0, stream>>>(partial, out_loss);
}

// Round 11
// 305.874 us; speedup vs baseline: 1.8806x; 1.0829x over previous
//
#include <hip/hip_runtime.h>

#define BATCH   262144
#define NCODE   1024
#define DIM     64
#define BLOCK   256
#define NBLK    (BATCH / BLOCK)   // 1024 blocks for emit
#define MARGIN2 2e-5f             // s''-units (= 4e-5 in dist units, validated r2-r10)
#define QCAP    65536
#define RTILE   16                // queued rows per fix block

// ws layout (bytes):
// [0, 8192)            double partial[1024]
// [8192, 12288)        float  c2[1024]
// [12288, 12292)       uint   qcount          (pad to 12544)
// [12544, 16640)       float  c2n[1024]       -- c2n[k] = -0.5f*c2[k]
// [16640, 278784)      ushort pack[131072]    -- codebook bf16 hi/lo, fragment-major
// [278784, 540928)     int    queue[65536]
// [540928, 803072)     float  cbT[65536]      -- codebook transposed [d][k]

typedef __attribute__((ext_vector_type(8))) short bf16x8;
typedef __attribute__((ext_vector_type(4))) float f32x4;

#define MFMA(a, b, c) __builtin_amdgcn_mfma_f32_16x16x32_bf16(a, b, c, 0, 0, 0)

// fp32 -> bf16 hi (RNE) + bf16 lo (RNE of exact residual)
__device__ __forceinline__ void split1(float f, unsigned short& h, unsigned short& l) {
    unsigned u = __float_as_uint(f);
    unsigned r = (u + 0x7fffu + ((u >> 16) & 1u)) >> 16;
    h = (unsigned short)r;
    float hf = __uint_as_float(r << 16);
    float lo = f - hf;                      // exact (Sterbenz)
    unsigned u2 = __float_as_uint(lo);
    l = (unsigned short)((u2 + 0x7fffu + ((u2 >> 16) & 1u)) >> 16);
}

// ---- fused prep: qcount zero, cbT transpose, exact c2 (+ -c2/2), pack ----
__global__ __launch_bounds__(256) void prep_kernel(
        const float* __restrict__ cb, float* __restrict__ c2, float* __restrict__ c2n,
        float* __restrict__ cbT, unsigned short* __restrict__ pack,
        unsigned int* __restrict__ qcount)
{
    const int gid = blockIdx.x * 256 + threadIdx.x;           // 0..65535
    if (gid == 0) *qcount = 0u;                               // re-zero each replay
    // transpose: cbT[d][k] = cb[k][d]
    cbT[(size_t)(gid & 63) * NCODE + (gid >> 6)] = cb[gid];
    // exact c2 (numpy pairwise order, 8 accumulators) — verified
    if (gid < NCODE) {
        const float* row = cb + (size_t)gid * DIM;
        float r[8];
#pragma unroll
        for (int j = 0; j < 8; ++j) r[j] = __fmul_rn(row[j], row[j]);
#pragma unroll
        for (int i = 8; i < DIM; i += 8) {
#pragma unroll
            for (int j = 0; j < 8; ++j) r[j] = __fadd_rn(r[j], __fmul_rn(row[i + j], row[i + j]));
        }
        const float v = __fadd_rn(__fadd_rn(__fadd_rn(r[0], r[1]), __fadd_rn(r[2], r[3])),
                                  __fadd_rn(__fadd_rn(r[4], r[5]), __fadd_rn(r[6], r[7])));
        c2[gid] = v;
        c2n[gid] = -0.5f * v;                 // exact scaling, screen-side only
    }
    // pack: fragment-major bf16 hi/lo
    if (gid < 4096) {
        const int t = gid >> 6, lane = gid & 63;
        const int c = t * 16 + (lane & 15);
        const int g = lane >> 4;
#pragma unroll
        for (int s = 0; s < 2; ++s) {
            const float* src = cb + (size_t)c * DIM + s * 32 + g * 8;
            bf16x8 hv, lv;
#pragma unroll
            for (int j = 0; j < 8; ++j) {
                unsigned short hh, ll; split1(src[j], hh, ll);
                hv[j] = (short)hh; lv[j] = (short)ll;
            }
            *(bf16x8*)(pack + ((size_t)(t * 4 + 2 * s + 0) * 64 + lane) * 8) = hv;
            *(bf16x8*)(pack + ((size_t)(t * 4 + 2 * s + 1) * 64 + lane) * 8) = lv;
        }
    }
}

// ---- MFMA screening (r5-verified, ~121 us): best/2nd of s''(k) = cross - c2/2 ----
__global__ __launch_bounds__(256) void screen_kernel(
        const float* __restrict__ z, const unsigned short* __restrict__ pack,
        const float* __restrict__ c2n, float* __restrict__ out_idx,
        int* __restrict__ queue, unsigned int* __restrict__ qcount)
{
    __shared__ __align__(16) unsigned short lds[2][8192];   // 2 x 16 KB chunks
    const int tid  = threadIdx.x;
    const int lane = tid & 63, wid = tid >> 6;
    const int col  = lane & 15, g = lane >> 4;
    const int rowbase = blockIdx.x * 128 + wid * 32;

    // A-frags: A[row = lane&15][k = 32*s + 8*g + j], in VGPRs for whole kernel
    bf16x8 Ah[2][2], Al[2][2];
#pragma unroll
    for (int rt = 0; rt < 2; ++rt)
#pragma unroll
        for (int s = 0; s < 2; ++s) {
            const float* zp = z + (size_t)(rowbase + rt * 16 + col) * DIM + s * 32 + g * 8;
            float tmp[8];
            *(float4*)(tmp)     = ((const float4*)zp)[0];
            *(float4*)(tmp + 4) = ((const float4*)zp)[1];
            bf16x8 hv, lv;
#pragma unroll
            for (int j = 0; j < 8; ++j) {
                unsigned short hh, ll; split1(tmp[j], hh, ll);
                hv[j] = (short)hh; lv[j] = (short)ll;
            }
            Ah[rt][s] = hv; Al[rt][s] = lv;
        }

    float b1[8], b2[8], bk[8];
#pragma unroll
    for (int i = 0; i < 8; ++i) {
        b1[i] = -__builtin_inff(); b2[i] = -__builtin_inff(); bk[i] = 0.f;
    }
    float codef = (float)col;

    // max-tracking; b2 = med3(s, b1_old, b2) is exact 2nd-max update given b2 <= b1
#define UPD(i, sv) { const float s_ = (sv); \
                     bk[i] = (s_ > b1[i]) ? codef : bk[i]; \
                     b2[i] = __builtin_amdgcn_fmed3f(s_, b1[i], b2[i]); \
                     b1[i] = fmaxf(b1[i], s_); }

    // stage one 16 KB chunk (4 tiles) via global_load_lds, 4 x 1KB segs per wave
#define STAGE(c, buf) { \
_Pragma("unroll") \
        for (int i_ = 0; i_ < 4; ++i_) { \
            const int seg_ = wid * 4 + i_; \
            const unsigned short* g_ = pack + (size_t)(c) * 8192 + seg_ * 512 + lane * 8; \
            unsigned short* l_ = &lds[buf][seg_ * 512]; \
            __builtin_amdgcn_global_load_lds( \
                (const __attribute__((address_space(1))) unsigned int*)g_, \
                (__attribute__((address_space(3))) unsigned int*)l_, 16, 0, 0); \
        } }

    int cur = 0;
    STAGE(0, 0);
    __syncthreads();
#pragma unroll 1
    for (int c = 0; c < 16; ++c) {
        if (c < 15) STAGE(c + 1, cur ^ 1);          // prefetch under compute
        float c2r[4];
#pragma unroll
        for (int u = 0; u < 4; ++u) c2r[u] = c2n[(c * 4 + u) * 16 + col];
        const unsigned short* buf = &lds[cur][0];
#pragma unroll
        for (int u = 0; u < 4; ++u) {
            const unsigned short* lb = buf + u * 2048;
            bf16x8 Bh0 = *(const bf16x8*)(lb +    0 + lane * 8);
            bf16x8 Bl0 = *(const bf16x8*)(lb +  512 + lane * 8);
            bf16x8 Bh1 = *(const bf16x8*)(lb + 1024 + lane * 8);
            bf16x8 Bl1 = *(const bf16x8*)(lb + 1536 + lane * 8);
            const float cv = c2r[u];
#pragma unroll
            for (int rt = 0; rt < 2; ++rt) {
                f32x4 acc = {cv, cv, cv, cv};       // C-in = -c2/2 (folds the fma away)
                // cross = zhi*chi + zhi*clo + zlo*chi (lo*lo dropped, ~2^-18 rel)
                acc = MFMA(Ah[rt][0], Bh0, acc); acc = MFMA(Ah[rt][1], Bh1, acc);
                acc = MFMA(Ah[rt][0], Bl0, acc); acc = MFMA(Al[rt][0], Bh0, acc);
                acc = MFMA(Ah[rt][1], Bl1, acc); acc = MFMA(Al[rt][1], Bh1, acc);
#pragma unroll
                for (int reg = 0; reg < 4; ++reg) UPD(rt * 4 + reg, acc[reg]);
            }
            codef += 16.f;
        }
        __syncthreads();                            // drains prefetch + WAR fence
        cur ^= 1;
    }
#undef UPD
#undef STAGE

    // reduce (b1, bk, b2) across the 16 lanes holding one row's 16 col-classes (max form)
#pragma unroll
    for (int i = 0; i < 8; ++i) {
        float v1 = b1[i], v2 = b2[i], vk = bk[i];
#pragma unroll
        for (int m = 1; m < 16; m <<= 1) {
            const float o1 = __shfl_xor(v1, m);
            const float o2 = __shfl_xor(v2, m);
            const float ok = __shfl_xor(vk, m);
            v2 = fmaxf(fmaxf(v2, o2), fminf(v1, o1));
            if (o1 > v1) vk = ok;                   // exact tie keeps own; tie flagged anyway
            v1 = fmaxf(v1, o1);
        }
        if (col == 0) {
            const int rt = i >> 2, reg = i & 3;
            const int row = rowbase + rt * 16 + g * 4 + reg;
            out_idx[row] = vk;
            if (v1 - v2 <= MARGIN2) {
                unsigned int p = atomicAdd(qcount, 1u);
                if (p < QCAP) queue[p] = row;
            }
        }
    }
}

// ---- exact fix-up: gather-GEMM, 16 queued rows per block ----
// Codebook traffic amortized: block reads each cbT[d] row ONCE for 16 rows
// (16 KB/row vs 256 KB/row before). Thread owns 4 contiguous codes; 16x4 static
// accumulators. Per-(row,code) math byte-identical to the verified path.
__global__ __launch_bounds__(256) void fix_kernel(
        const float* __restrict__ z, const float* __restrict__ cbT,
        const float* __restrict__ c2, const int* __restrict__ queue,
        const unsigned int* __restrict__ qcount, float* __restrict__ out_idx)
{
    __shared__ float zT[DIM][RTILE + 4];    // [d][r], stride 20 floats (80B, 16B-aligned)
    __shared__ float z2s[RTILE];
    __shared__ int   rows[RTILE];
    __shared__ float rvs[4][RTILE];
    __shared__ int   ris[4][RTILE];
    const int tid  = threadIdx.x;
    const int lane = tid & 63, wid = tid >> 6;
    const unsigned int nq = *qcount;
    const bool overflow = (nq > QCAP);      // fallback: exact-fix every row
    const unsigned int total = overflow ? (unsigned int)BATCH : nq;

    // per-thread constants (hoisted across tiles)
    const int k0 = tid * 4;
    const float4 c2v = *(const float4*)(c2 + k0);

    for (unsigned int base = blockIdx.x * RTILE; base < total;
         base += gridDim.x * RTILE) {
        const int rcount = (int)min((unsigned int)RTILE, total - base);
        __syncthreads();                    // previous tile fully consumed
        if (tid < RTILE) {
            const int qi = (int)base + min(tid, rcount - 1);
            rows[tid] = overflow ? qi : queue[qi];
        }
        __syncthreads();
        // stage z: thread t -> row r=t>>4, dim-quad q=t&15 (coalesced 16B loads)
        {
            const int r = tid >> 4, q = tid & 15;
            const float4 v = *(const float4*)(z + (size_t)rows[r] * DIM + 4 * q);
            zT[4 * q + 0][r] = v.x; zT[4 * q + 1][r] = v.y;
            zT[4 * q + 2][r] = v.z; zT[4 * q + 3][r] = v.w;
        }
        __syncthreads();
        // z2 per row: numpy pairwise, 8 accumulators (exact verified order)
        if (tid < RTILE) {
            float r8[8];
#pragma unroll
            for (int j = 0; j < 8; ++j) { const float v = zT[j][tid]; r8[j] = __fmul_rn(v, v); }
#pragma unroll
            for (int i = 1; i < 8; ++i)
#pragma unroll
                for (int j = 0; j < 8; ++j) {
                    const float v = zT[8 * i + j][tid];
                    r8[j] = __fadd_rn(r8[j], __fmul_rn(v, v));
                }
            z2s[tid] = __fadd_rn(__fadd_rn(__fadd_rn(r8[0], r8[1]), __fadd_rn(r8[2], r8[3])),
                                 __fadd_rn(__fadd_rn(r8[4], r8[5]), __fadd_rn(r8[6], r8[7])));
        }
        __syncthreads();

        // main: ascending-d sequential FMA chains, 16 rows x 4 codes per thread
        float acc[RTILE][4];
#pragma unroll
        for (int r = 0; r < RTILE; ++r)
#pragma unroll
            for (int j = 0; j < 4; ++j) acc[r][j] = 0.f;
#pragma unroll 2
        for (int d = 0; d < DIM; ++d) {
            const float4 cv = *(const float4*)(cbT + (size_t)d * NCODE + k0);
            const float* zr = &zT[d][0];    // broadcast b128 reads (same addr all lanes)
#pragma unroll
            for (int r = 0; r < RTILE; ++r) {
                const float zd = zr[r];
                acc[r][0] = __fmaf_rn(zd, cv.x, acc[r][0]);
                acc[r][1] = __fmaf_rn(zd, cv.y, acc[r][1]);
                acc[r][2] = __fmaf_rn(zd, cv.z, acc[r][2]);
                acc[r][3] = __fmaf_rn(zd, cv.w, acc[r][3]);
            }
        }

        // per-row argmin: thread-local (ascending k), wave shfl-reduce, 4-wave merge
        const float c2a[4] = {c2v.x, c2v.y, c2v.z, c2v.w};
#pragma unroll
        for (int r = 0; r < RTILE; ++r) {
            const float z2 = z2s[r];
            float best = __builtin_inff();
            int bestk = NCODE;
#pragma unroll
            for (int j = 0; j < 4; ++j) {
                const float dist = __fadd_rn(__fmaf_rn(-2.0f, acc[r][j], z2), c2a[j]);
                if (dist < best) { best = dist; bestk = k0 + j; }   // strict <, asc k
            }
#pragma unroll
            for (int m = 1; m < 64; m <<= 1) {       // lanes hold ascending k-ranges
                const float ob = __shfl_xor(best, m);
                const int   ok = __shfl_xor(bestk, m);
                if (ob < best || (ob == best && ok < bestk)) { best = ob; bestk = ok; }
            }
            if (lane == 0) { rvs[wid][r] = best; ris[wid][r] = bestk; }
        }
        __syncthreads();
        if (tid < rcount) {                          // waves hold ascending k-ranges
            float v = rvs[0][tid]; int vi = ris[0][tid];
#pragma unroll
            for (int w = 1; w < 4; ++w) {
                const float ov = rvs[w][tid]; const int oi = ris[w][tid];
                if (ov < v || (ov == v && oi < vi)) { v = ov; vi = oi; }
            }
            out_idx[rows[tid]] = (float)vi;
        }
    }
}

// ---- epilogue: gather z_q, straight-through output, loss partial (verbatim) ----
__global__ __launch_bounds__(BLOCK) void emit_kernel(
        const float* __restrict__ z, const float* __restrict__ cb,
        const float* __restrict__ out_idx, float* __restrict__ out_zq,
        double* __restrict__ partial)
{
    const int b = blockIdx.x * BLOCK + threadIdx.x;
    const int bestk = (int)out_idx[b];
    const float* cq = cb + (size_t)bestk * DIM;
    const float4* zv = (const float4*)(z + (size_t)b * DIM);
    const float4* qv = (const float4*)cq;
    float4* ov = (float4*)(out_zq + (size_t)b * DIM);
    double lsum = 0.0;
#pragma unroll
    for (int i = 0; i < DIM / 4; ++i) {
        float4 qq = qv[i], zl = zv[i];
        float qa[4] = {qq.x, qq.y, qq.z, qq.w};
        float za[4] = {zl.x, zl.y, zl.z, zl.w};
        float o[4];
#pragma unroll
        for (int j = 0; j < 4; ++j) {
            const float t = __fsub_rn(qa[j], za[j]);
            o[j] = __fadd_rn(za[j], t);
            lsum += (double)t * (double)t;
        }
        float4 vv; vv.x = o[0]; vv.y = o[1]; vv.z = o[2]; vv.w = o[3];
        ov[i] = vv;
    }

    __shared__ double sred[BLOCK];
    sred[threadIdx.x] = lsum;
    __syncthreads();
#pragma unroll
    for (int s = BLOCK / 2; s > 0; s >>= 1) {
        if (threadIdx.x < s) sred[threadIdx.x] += sred[threadIdx.x + s];
        __syncthreads();
    }
    if (threadIdx.x == 0) partial[blockIdx.x] = sred[0];
}

__global__ void loss_kernel(const double* __restrict__ partial, float* __restrict__ out_loss) {
    __shared__ double sred[256];
    double s = 0.0;
    for (int i = threadIdx.x; i < NBLK; i += 256) s += partial[i];
    sred[threadIdx.x] = s;
    __syncthreads();
#pragma unroll
    for (int st = 128; st > 0; st >>= 1) {
        if (threadIdx.x < st) sred[threadIdx.x] += sred[threadIdx.x + st];
        __syncthreads();
    }
    if (threadIdx.x == 0) {
        const double mean = sred[0] / (double)((size_t)BATCH * DIM);
        const float L = (float)mean;
        out_loss[0] = __fadd_rn(L, __fmul_rn(0.25f, L));
    }
}

extern "C" void kernel_launch(void* const* d_in, const int* in_sizes, int n_in,
                              void* d_out, int out_size, void* d_ws, size_t ws_size,
                              hipStream_t stream) {
    (void)in_sizes; (void)n_in; (void)out_size; (void)ws_size;
    const float* z  = (const float*)d_in[0];
    const float* cb = (const float*)d_in[1];
    float* out      = (float*)d_out;
    float* out_zq   = out;
    float* out_loss = out + (size_t)BATCH * DIM;
    float* out_idx  = out + (size_t)BATCH * DIM + 1;
    double* partial = (double*)d_ws;
    float* c2       = (float*)((char*)d_ws + 8192);
    unsigned int* qcount = (unsigned int*)((char*)d_ws + 12288);
    float* c2n      = (float*)((char*)d_ws + 12544);
    unsigned short* pack = (unsigned short*)((char*)d_ws + 16640);
    int* queue      = (int*)((char*)d_ws + 278784);
    float* cbT      = (float*)((char*)d_ws + 540928);

    prep_kernel<<<256, 256, 0, stream>>>(cb, c2, c2n, cbT, pack, qcount);
    screen_kernel<<<BATCH / 128, 256, 0, stream>>>(z, pack, c2n, out_idx, queue, qcount);
    fix_kernel<<<2048, 256, 0, stream>>>(z, cbT, c2, queue, qcount, out_idx);
    emit_kernel<<<NBLK, BLOCK, 0, stream>>>(z, cb, out_idx, out_zq, partial);
    loss_kernel<<<1, 256, 0, stream>>>(partial, out_loss);
}

// Round 12
// 298.129 us; speedup vs baseline: 1.9294x; 1.0260x over previous
//
#include <hip/hip_runtime.h>

#define BATCH   262144
#define NCODE   1024
#define DIM     64
#define BLOCK   256
#define NBLK    (BATCH / BLOCK)   // 1024 blocks for emit
#define MARGIN2 2e-5f             // s''-units (= 4e-5 in dist units, validated r2-r11)
#define QCAP    65536
#define RTILE   16                // queued rows per fix block

// ws layout (bytes):
// [0, 8192)            double partial[1024]
// [8192, 12288)        float  c2[1024]
// [12288, 12292)       uint   qcount          (pad to 12544)
// [12544, 16640)       float  c2n[1024]       -- c2n[k] = -0.5f*c2[k]
// [16640, 278784)      ushort pack[131072]    -- codebook bf16 hi/lo, fragment-major
// [278784, 540928)     int    queue[65536]
// [540928, 803072)     float  cbT[65536]      -- codebook transposed [d][k]

typedef __attribute__((ext_vector_type(8))) short bf16x8;
typedef __attribute__((ext_vector_type(4))) float f32x4;

#define MFMA(a, b, c) __builtin_amdgcn_mfma_f32_16x16x32_bf16(a, b, c, 0, 0, 0)

// fp32 -> bf16 hi (RNE) + bf16 lo (RNE of exact residual)
__device__ __forceinline__ void split1(float f, unsigned short& h, unsigned short& l) {
    unsigned u = __float_as_uint(f);
    unsigned r = (u + 0x7fffu + ((u >> 16) & 1u)) >> 16;
    h = (unsigned short)r;
    float hf = __uint_as_float(r << 16);
    float lo = f - hf;                      // exact (Sterbenz)
    unsigned u2 = __float_as_uint(lo);
    l = (unsigned short)((u2 + 0x7fffu + ((u2 >> 16) & 1u)) >> 16);
}

// ---- fused prep: qcount zero, cbT transpose, exact c2 (+ -c2/2), pack ----
__global__ __launch_bounds__(256) void prep_kernel(
        const float* __restrict__ cb, float* __restrict__ c2, float* __restrict__ c2n,
        float* __restrict__ cbT, unsigned short* __restrict__ pack,
        unsigned int* __restrict__ qcount)
{
    const int gid = blockIdx.x * 256 + threadIdx.x;           // 0..65535
    if (gid == 0) *qcount = 0u;                               // re-zero each replay
    // transpose: cbT[d][k] = cb[k][d]
    cbT[(size_t)(gid & 63) * NCODE + (gid >> 6)] = cb[gid];
    // exact c2 (numpy pairwise order, 8 accumulators) — verified
    if (gid < NCODE) {
        const float* row = cb + (size_t)gid * DIM;
        float r[8];
#pragma unroll
        for (int j = 0; j < 8; ++j) r[j] = __fmul_rn(row[j], row[j]);
#pragma unroll
        for (int i = 8; i < DIM; i += 8) {
#pragma unroll
            for (int j = 0; j < 8; ++j) r[j] = __fadd_rn(r[j], __fmul_rn(row[i + j], row[i + j]));
        }
        const float v = __fadd_rn(__fadd_rn(__fadd_rn(r[0], r[1]), __fadd_rn(r[2], r[3])),
                                  __fadd_rn(__fadd_rn(r[4], r[5]), __fadd_rn(r[6], r[7])));
        c2[gid] = v;
        c2n[gid] = -0.5f * v;                 // exact scaling, screen-side only
    }
    // pack: fragment-major bf16 hi/lo
    if (gid < 4096) {
        const int t = gid >> 6, lane = gid & 63;
        const int c = t * 16 + (lane & 15);
        const int g = lane >> 4;
#pragma unroll
        for (int s = 0; s < 2; ++s) {
            const float* src = cb + (size_t)c * DIM + s * 32 + g * 8;
            bf16x8 hv, lv;
#pragma unroll
            for (int j = 0; j < 8; ++j) {
                unsigned short hh, ll; split1(src[j], hh, ll);
                hv[j] = (short)hh; lv[j] = (short)ll;
            }
            *(bf16x8*)(pack + ((size_t)(t * 4 + 2 * s + 0) * 64 + lane) * 8) = hv;
            *(bf16x8*)(pack + ((size_t)(t * 4 + 2 * s + 1) * 64 + lane) * 8) = lv;
        }
    }
}

// ---- MFMA screening: best/2nd of s''(k) = cross(k) - c2[k]/2 ----
// argmax(s'') == argmin(dist). wave = 32 rows (2 row-tiles); block = 4 waves; grid 2048.
// r12 delta vs r5-verified: 8 KB chunks (2 tiles) double-buffered -> LDS 16 KB/block
// -> 8 blocks/CU resident (was 3 at 32 KB). Barrier stalls of one block now overlap
// with 7 de-phased neighbors. + T5 setprio around each 6-MFMA cluster.
__global__ __launch_bounds__(256) void screen_kernel(
        const float* __restrict__ z, const unsigned short* __restrict__ pack,
        const float* __restrict__ c2n, float* __restrict__ out_idx,
        int* __restrict__ queue, unsigned int* __restrict__ qcount)
{
    __shared__ __align__(16) unsigned short lds[2][4096];   // 2 x 8 KB chunks
    const int tid  = threadIdx.x;
    const int lane = tid & 63, wid = tid >> 6;
    const int col  = lane & 15, g = lane >> 4;
    const int rowbase = blockIdx.x * 128 + wid * 32;

    // A-frags: A[row = lane&15][k = 32*s + 8*g + j], in VGPRs for whole kernel
    bf16x8 Ah[2][2], Al[2][2];
#pragma unroll
    for (int rt = 0; rt < 2; ++rt)
#pragma unroll
        for (int s = 0; s < 2; ++s) {
            const float* zp = z + (size_t)(rowbase + rt * 16 + col) * DIM + s * 32 + g * 8;
            float tmp[8];
            *(float4*)(tmp)     = ((const float4*)zp)[0];
            *(float4*)(tmp + 4) = ((const float4*)zp)[1];
            bf16x8 hv, lv;
#pragma unroll
            for (int j = 0; j < 8; ++j) {
                unsigned short hh, ll; split1(tmp[j], hh, ll);
                hv[j] = (short)hh; lv[j] = (short)ll;
            }
            Ah[rt][s] = hv; Al[rt][s] = lv;
        }

    float b1[8], b2[8], bk[8];
#pragma unroll
    for (int i = 0; i < 8; ++i) {
        b1[i] = -__builtin_inff(); b2[i] = -__builtin_inff(); bk[i] = 0.f;
    }
    float codef = (float)col;

    // max-tracking; b2 = med3(s, b1_old, b2) is exact 2nd-max update given b2 <= b1
#define UPD(i, sv) { const float s_ = (sv); \
                     bk[i] = (s_ > b1[i]) ? codef : bk[i]; \
                     b2[i] = __builtin_amdgcn_fmed3f(s_, b1[i], b2[i]); \
                     b1[i] = fmaxf(b1[i], s_); }

    // stage one 8 KB chunk (2 tiles = 8 segs of 1 KB) via global_load_lds width-16;
    // wave wid stages segs {2*wid, 2*wid+1}
#define STAGE(c, buf) { \
_Pragma("unroll") \
        for (int i_ = 0; i_ < 2; ++i_) { \
            const int seg_ = wid * 2 + i_; \
            const unsigned short* g_ = pack + (size_t)(c) * 4096 + seg_ * 512 + lane * 8; \
            unsigned short* l_ = &lds[buf][seg_ * 512]; \
            __builtin_amdgcn_global_load_lds( \
                (const __attribute__((address_space(1))) unsigned int*)g_, \
                (__attribute__((address_space(3))) unsigned int*)l_, 16, 0, 0); \
        } }

    int cur = 0;
    STAGE(0, 0);
    __syncthreads();
#pragma unroll 1
    for (int c = 0; c < 32; ++c) {
        if (c < 31) STAGE(c + 1, cur ^ 1);          // prefetch under compute
        float c2r[2];
#pragma unroll
        for (int u = 0; u < 2; ++u) c2r[u] = c2n[(c * 2 + u) * 16 + col];
        const unsigned short* buf = &lds[cur][0];
#pragma unroll
        for (int u = 0; u < 2; ++u) {
            const unsigned short* lb = buf + u * 2048;
            bf16x8 Bh0 = *(const bf16x8*)(lb +    0 + lane * 8);
            bf16x8 Bl0 = *(const bf16x8*)(lb +  512 + lane * 8);
            bf16x8 Bh1 = *(const bf16x8*)(lb + 1024 + lane * 8);
            bf16x8 Bl1 = *(const bf16x8*)(lb + 1536 + lane * 8);
            const float cv = c2r[u];
#pragma unroll
            for (int rt = 0; rt < 2; ++rt) {
                f32x4 acc = {cv, cv, cv, cv};       // C-in = -c2/2 (folds the fma away)
                __builtin_amdgcn_s_setprio(1);
                // cross = zhi*chi + zhi*clo + zlo*chi (lo*lo dropped, ~2^-18 rel)
                acc = MFMA(Ah[rt][0], Bh0, acc); acc = MFMA(Ah[rt][1], Bh1, acc);
                acc = MFMA(Ah[rt][0], Bl0, acc); acc = MFMA(Al[rt][0], Bh0, acc);
                acc = MFMA(Ah[rt][1], Bl1, acc); acc = MFMA(Al[rt][1], Bh1, acc);
                __builtin_amdgcn_s_setprio(0);
#pragma unroll
                for (int reg = 0; reg < 4; ++reg) UPD(rt * 4 + reg, acc[reg]);
            }
            codef += 16.f;
        }
        __syncthreads();                            // drains prefetch + WAR fence
        cur ^= 1;
    }
#undef UPD
#undef STAGE

    // reduce (b1, bk, b2) across the 16 lanes holding one row's 16 col-classes (max form)
#pragma unroll
    for (int i = 0; i < 8; ++i) {
        float v1 = b1[i], v2 = b2[i], vk = bk[i];
#pragma unroll
        for (int m = 1; m < 16; m <<= 1) {
            const float o1 = __shfl_xor(v1, m);
            const float o2 = __shfl_xor(v2, m);
            const float ok = __shfl_xor(vk, m);
            v2 = fmaxf(fmaxf(v2, o2), fminf(v1, o1));
            if (o1 > v1) vk = ok;                   // exact tie keeps own; tie flagged anyway
            v1 = fmaxf(v1, o1);
        }
        if (col == 0) {
            const int rt = i >> 2, reg = i & 3;
            const int row = rowbase + rt * 16 + g * 4 + reg;
            out_idx[row] = vk;
            if (v1 - v2 <= MARGIN2) {
                unsigned int p = atomicAdd(qcount, 1u);
                if (p < QCAP) queue[p] = row;
            }
        }
    }
}

// ---- exact fix-up: gather-GEMM, 16 queued rows per block (r11-verified) ----
__global__ __launch_bounds__(256) void fix_kernel(
        const float* __restrict__ z, const float* __restrict__ cbT,
        const float* __restrict__ c2, const int* __restrict__ queue,
        const unsigned int* __restrict__ qcount, float* __restrict__ out_idx)
{
    __shared__ float zT[DIM][RTILE + 4];    // [d][r], stride 20 floats
    __shared__ float z2s[RTILE];
    __shared__ int   rows[RTILE];
    __shared__ float rvs[4][RTILE];
    __shared__ int   ris[4][RTILE];
    const int tid  = threadIdx.x;
    const int lane = tid & 63, wid = tid >> 6;
    const unsigned int nq = *qcount;
    const bool overflow = (nq > QCAP);      // fallback: exact-fix every row
    const unsigned int total = overflow ? (unsigned int)BATCH : nq;

    const int k0 = tid * 4;
    const float4 c2v = *(const float4*)(c2 + k0);

    for (unsigned int base = blockIdx.x * RTILE; base < total;
         base += gridDim.x * RTILE) {
        const int rcount = (int)min((unsigned int)RTILE, total - base);
        __syncthreads();                    // previous tile fully consumed
        if (tid < RTILE) {
            const int qi = (int)base + min(tid, rcount - 1);
            rows[tid] = overflow ? qi : queue[qi];
        }
        __syncthreads();
        // stage z: thread t -> row r=t>>4, dim-quad q=t&15 (coalesced 16B loads)
        {
            const int r = tid >> 4, q = tid & 15;
            const float4 v = *(const float4*)(z + (size_t)rows[r] * DIM + 4 * q);
            zT[4 * q + 0][r] = v.x; zT[4 * q + 1][r] = v.y;
            zT[4 * q + 2][r] = v.z; zT[4 * q + 3][r] = v.w;
        }
        __syncthreads();
        // z2 per row: numpy pairwise, 8 accumulators (exact verified order)
        if (tid < RTILE) {
            float r8[8];
#pragma unroll
            for (int j = 0; j < 8; ++j) { const float v = zT[j][tid]; r8[j] = __fmul_rn(v, v); }
#pragma unroll
            for (int i = 1; i < 8; ++i)
#pragma unroll
                for (int j = 0; j < 8; ++j) {
                    const float v = zT[8 * i + j][tid];
                    r8[j] = __fadd_rn(r8[j], __fmul_rn(v, v));
                }
            z2s[tid] = __fadd_rn(__fadd_rn(__fadd_rn(r8[0], r8[1]), __fadd_rn(r8[2], r8[3])),
                                 __fadd_rn(__fadd_rn(r8[4], r8[5]), __fadd_rn(r8[6], r8[7])));
        }
        __syncthreads();

        // main: ascending-d sequential FMA chains, 16 rows x 4 codes per thread
        float acc[RTILE][4];
#pragma unroll
        for (int r = 0; r < RTILE; ++r)
#pragma unroll
            for (int j = 0; j < 4; ++j) acc[r][j] = 0.f;
#pragma unroll 2
        for (int d = 0; d < DIM; ++d) {
            const float4 cv = *(const float4*)(cbT + (size_t)d * NCODE + k0);
            const float* zr = &zT[d][0];    // broadcast reads (same addr all lanes)
#pragma unroll
            for (int r = 0; r < RTILE; ++r) {
                const float zd = zr[r];
                acc[r][0] = __fmaf_rn(zd, cv.x, acc[r][0]);
                acc[r][1] = __fmaf_rn(zd, cv.y, acc[r][1]);
                acc[r][2] = __fmaf_rn(zd, cv.z, acc[r][2]);
                acc[r][3] = __fmaf_rn(zd, cv.w, acc[r][3]);
            }
        }

        // per-row argmin: thread-local (ascending k), wave shfl-reduce, 4-wave merge
        const float c2a[4] = {c2v.x, c2v.y, c2v.z, c2v.w};
#pragma unroll
        for (int r = 0; r < RTILE; ++r) {
            const float z2 = z2s[r];
            float best = __builtin_inff();
            int bestk = NCODE;
#pragma unroll
            for (int j = 0; j < 4; ++j) {
                const float dist = __fadd_rn(__fmaf_rn(-2.0f, acc[r][j], z2), c2a[j]);
                if (dist < best) { best = dist; bestk = k0 + j; }   // strict <, asc k
            }
#pragma unroll
            for (int m = 1; m < 64; m <<= 1) {       // lanes hold ascending k-ranges
                const float ob = __shfl_xor(best, m);
                const int   ok = __shfl_xor(bestk, m);
                if (ob < best || (ob == best && ok < bestk)) { best = ob; bestk = ok; }
            }
            if (lane == 0) { rvs[wid][r] = best; ris[wid][r] = bestk; }
        }
        __syncthreads();
        if (tid < rcount) {                          // waves hold ascending k-ranges
            float v = rvs[0][tid]; int vi = ris[0][tid];
#pragma unroll
            for (int w = 1; w < 4; ++w) {
                const float ov = rvs[w][tid]; const int oi = ris[w][tid];
                if (ov < v || (ov == v && oi < vi)) { v = ov; vi = oi; }
            }
            out_idx[rows[tid]] = (float)vi;
        }
    }
}

// ---- epilogue: gather z_q, straight-through output, loss partial (verbatim) ----
__global__ __launch_bounds__(BLOCK) void emit_kernel(
        const float* __restrict__ z, const float* __restrict__ cb,
        const float* __restrict__ out_idx, float* __restrict__ out_zq,
        double* __restrict__ partial)
{
    const int b = blockIdx.x * BLOCK + threadIdx.x;
    const int bestk = (int)out_idx[b];
    const float* cq = cb + (size_t)bestk * DIM;
    const float4* zv = (const float4*)(z + (size_t)b * DIM);
    const float4* qv = (const float4*)cq;
    float4* ov = (float4*)(out_zq + (size_t)b * DIM);
    double lsum = 0.0;
#pragma unroll
    for (int i = 0; i < DIM / 4; ++i) {
        float4 qq = qv[i], zl = zv[i];
        float qa[4] = {qq.x, qq.y, qq.z, qq.w};
        float za[4] = {zl.x, zl.y, zl.z, zl.w};
        float o[4];
#pragma unroll
        for (int j = 0; j < 4; ++j) {
            const float t = __fsub_rn(qa[j], za[j]);
            o[j] = __fadd_rn(za[j], t);
            lsum += (double)t * (double)t;
        }
        float4 vv; vv.x = o[0]; vv.y = o[1]; vv.z = o[2]; vv.w = o[3];
        ov[i] = vv;
    }

    __shared__ double sred[BLOCK];
    sred[threadIdx.x] = lsum;
    __syncthreads();
#pragma unroll
    for (int s = BLOCK / 2; s > 0; s >>= 1) {
        if (threadIdx.x < s) sred[threadIdx.x] += sred[threadIdx.x + s];
        __syncthreads();
    }
    if (threadIdx.x == 0) partial[blockIdx.x] = sred[0];
}

__global__ void loss_kernel(const double* __restrict__ partial, float* __restrict__ out_loss) {
    __shared__ double sred[256];
    double s = 0.0;
    for (int i = threadIdx.x; i < NBLK; i += 256) s += partial[i];
    sred[threadIdx.x] = s;
    __syncthreads();
#pragma unroll
    for (int st = 128; st > 0; st >>= 1) {
        if (threadIdx.x < st) sred[threadIdx.x] += sred[threadIdx.x + st];
        __syncthreads();
    }
    if (threadIdx.x == 0) {
        const double mean = sred[0] / (double)((size_t)BATCH * DIM);
        const float L = (float)mean;
        out_loss[0] = __fadd_rn(L, __fmul_rn(0.25f, L));
    }
}

extern "C" void kernel_launch(void* const* d_in, const int* in_sizes, int n_in,
                              void* d_out, int out_size, void* d_ws, size_t ws_size,
                              hipStream_t stream) {
    (void)in_sizes; (void)n_in; (void)out_size; (void)ws_size;
    const float* z  = (const float*)d_in[0];
    const float* cb = (const float*)d_in[1];
    float* out      = (float*)d_out;
    float* out_zq   = out;
    float* out_loss = out + (size_t)BATCH * DIM;
    float* out_idx  = out + (size_t)BATCH * DIM + 1;
    double* partial = (double*)d_ws;
    float* c2       = (float*)((char*)d_ws + 8192);
    unsigned int* qcount = (unsigned int*)((char*)d_ws + 12288);
    float* c2n      = (float*)((char*)d_ws + 12544);
    unsigned short* pack = (unsigned short*)((char*)d_ws + 16640);
    int* queue      = (int*)((char*)d_ws + 278784);
    float* cbT      = (float*)((char*)d_ws + 540928);

    prep_kernel<<<256, 256, 0, stream>>>(cb, c2, c2n, cbT, pack, qcount);
    screen_kernel<<<BATCH / 128, 256, 0, stream>>>(z, pack, c2n, out_idx, queue, qcount);
    fix_kernel<<<4096, 256, 0, stream>>>(z, cbT, c2, queue, qcount, out_idx);
    emit_kernel<<<NBLK, BLOCK, 0, stream>>>(z, cb, out_idx, out_zq, partial);
    loss_kernel<<<1, 256, 0, stream>>>(partial, out_loss);
}